// Round 3
// baseline (1640.840 us; speedup 1.0000x reference)
//
#include <hip/hip_runtime.h>
#include <cstdint>

typedef unsigned short u16;
typedef __attribute__((ext_vector_type(8))) short bf16x8;
typedef __attribute__((ext_vector_type(4))) float f32x4;
typedef __attribute__((ext_vector_type(8))) unsigned short u16x8;

constexpr int NB = 8;       // batch
constexpr int SEQ = 1024;   // sequence
constexpr int NH = 12;      // heads
constexpr int DM = 768;     // model dim
constexpr int DH = 64;      // head dim

__device__ __forceinline__ u16 f2bf(float f) {
  unsigned int x = __builtin_bit_cast(unsigned int, f);
  x += 0x7fffu + ((x >> 16) & 1u);
  return (u16)(x >> 16);
}

__device__ __forceinline__ float bf2f(u16 u) {
  return __builtin_bit_cast(float, (unsigned int)u << 16);
}

#if __has_builtin(__builtin_amdgcn_exp2f)
__device__ __forceinline__ float fexp2(float x) { return __builtin_amdgcn_exp2f(x); }
#else
__device__ __forceinline__ float fexp2(float x) { return exp2f(x); }
#endif

typedef __attribute__((address_space(1))) void* as1vp;
typedef __attribute__((address_space(3))) void* as3vp;

__device__ __forceinline__ void load_lds16(const u16* g, u16* l) {
  __builtin_amdgcn_global_load_lds((as1vp)(g), (as3vp)(l), 16, 0, 0);
}

// C = A @ B. A [M,K] row-major bf16 (lda), B TRANSPOSED: BT [N,K] bf16 (ldb).
// 16x16x32 bf16 MFMA, TM x TN tile, BK=32, 256 threads (2x2 waves).
//  EPI 4: out proj -> FP32 [TOK,DM], + fp32 bias + fp32 residual
template<int TM, int TN, int EPI>
__global__ __launch_bounds__(256)
void gemm_bt(const u16* __restrict__ A, int lda, long long strideA,
             const u16* __restrict__ BT, int ldb, long long strideBT,
             const float* __restrict__ bias,
             const float* __restrict__ extra,
             void* __restrict__ outp,
             int K)
{
  constexpr int BK = 32;
  constexpr int WM = TM / 2, WN = TN / 2;
  constexpr int FM = WM / 16, FN = WN / 16;
  __shared__ u16 As[TM * BK];
  __shared__ u16 Bs[TN * BK];
  const int tid = threadIdx.x;
  const int w = tid >> 6, l = tid & 63;
  const int z = blockIdx.z;
  const u16* Az = A + (long long)z * strideA;
  const u16* Bz = BT + (long long)z * strideBT;
  const int m0 = blockIdx.x * TM, n0 = blockIdx.y * TN;
  const int wm = (w & 1) * WM, wn = (w >> 1) * WN;
  const int quad = l >> 4, md = l & 15;

  f32x4 acc[FM][FN];
  f32x4 zero = {0.f, 0.f, 0.f, 0.f};
  #pragma unroll
  for (int i = 0; i < FM; ++i)
    #pragma unroll
    for (int j = 0; j < FN; ++j) acc[i][j] = zero;

  for (int k0 = 0; k0 < K; k0 += BK) {
    __syncthreads();
    #pragma unroll
    for (int r = 0; r < TM / 64; ++r) {
      int lin = r * 256 + tid;
      int row = lin >> 2, ch = lin & 3;
      load_lds16(Az + (long long)(m0 + row) * lda + k0 + ch * 8, &As[lin * 8]);
    }
    #pragma unroll
    for (int r = 0; r < TN / 64; ++r) {
      int lin = r * 256 + tid;
      int row = lin >> 2, ch = lin & 3;
      load_lds16(Bz + (long long)(n0 + row) * ldb + k0 + ch * 8, &Bs[lin * 8]);
    }
    __syncthreads();
    bf16x8 af[FM], bfr[FN];
    #pragma unroll
    for (int i = 0; i < FM; ++i)
      af[i] = *(const bf16x8*)&As[(wm + i * 16 + md) * BK + quad * 8];
    #pragma unroll
    for (int j = 0; j < FN; ++j)
      bfr[j] = *(const bf16x8*)&Bs[(wn + j * 16 + md) * BK + quad * 8];
    #pragma unroll
    for (int i = 0; i < FM; ++i)
      #pragma unroll
      for (int j = 0; j < FN; ++j)
        acc[i][j] = __builtin_amdgcn_mfma_f32_16x16x32_bf16(af[i], bfr[j], acc[i][j], 0, 0, 0);
  }

  #pragma unroll
  for (int i = 0; i < FM; ++i) {
    #pragma unroll
    for (int j = 0; j < FN; ++j) {
      #pragma unroll
      for (int r = 0; r < 4; ++r) {
        int grow = m0 + wm + i * 16 + quad * 4 + r;
        int gcol = n0 + wn + j * 16 + md;
        float v = acc[i][j][r];
        float vv = v + bias[gcol] + extra[(long long)grow * DM + gcol];
        ((float*)outp)[(long long)grow * DM + gcol] = vv;
      }
    }
  }
}

// Merged QKV projection: grid (64, 6, 3); z=0 Q, z=1 K (head-split layout),
// z=2 V (transposed [B,H,DH,S] layout). A slots and W slots contiguous.
__global__ __launch_bounds__(256)
void gemm_qkv(const u16* __restrict__ Abase, const u16* __restrict__ Wbase,
              const float* __restrict__ bq, const float* __restrict__ bk,
              const float* __restrict__ bv, u16* __restrict__ outbase)
{
  constexpr int TM = 128, TN = 128, BK = 32;
  constexpr int WM = 64, WN = 64, FM = 4, FN = 4;
  __shared__ u16 As[TM * BK];
  __shared__ u16 Bs[TN * BK];
  const int tid = threadIdx.x;
  const int w = tid >> 6, l = tid & 63;
  const int z = blockIdx.z;
  const long long TOKDM = (long long)NB * SEQ * DM;
  const u16* Az = Abase + (long long)z * TOKDM;
  const u16* Bz = Wbase + (long long)z * DM * DM;
  const float* bias = z == 0 ? bq : z == 1 ? bk : bv;
  u16* o = outbase + (long long)z * TOKDM;
  const int m0 = blockIdx.x * TM, n0 = blockIdx.y * TN;
  const int wm = (w & 1) * WM, wn = (w >> 1) * WN;
  const int quad = l >> 4, md = l & 15;

  f32x4 acc[FM][FN];
  f32x4 zero = {0.f, 0.f, 0.f, 0.f};
  #pragma unroll
  for (int i = 0; i < FM; ++i)
    #pragma unroll
    for (int j = 0; j < FN; ++j) acc[i][j] = zero;

  for (int k0 = 0; k0 < DM; k0 += BK) {
    __syncthreads();
    #pragma unroll
    for (int r = 0; r < 2; ++r) {
      int lin = r * 256 + tid;
      int row = lin >> 2, ch = lin & 3;
      load_lds16(Az + (long long)(m0 + row) * DM + k0 + ch * 8, &As[lin * 8]);
    }
    #pragma unroll
    for (int r = 0; r < 2; ++r) {
      int lin = r * 256 + tid;
      int row = lin >> 2, ch = lin & 3;
      load_lds16(Bz + (long long)(n0 + row) * DM + k0 + ch * 8, &Bs[lin * 8]);
    }
    __syncthreads();
    bf16x8 af[FM], bfr[FN];
    #pragma unroll
    for (int i = 0; i < FM; ++i)
      af[i] = *(const bf16x8*)&As[(wm + i * 16 + md) * BK + quad * 8];
    #pragma unroll
    for (int j = 0; j < FN; ++j)
      bfr[j] = *(const bf16x8*)&Bs[(wn + j * 16 + md) * BK + quad * 8];
    #pragma unroll
    for (int i = 0; i < FM; ++i)
      #pragma unroll
      for (int j = 0; j < FN; ++j)
        acc[i][j] = __builtin_amdgcn_mfma_f32_16x16x32_bf16(af[i], bfr[j], acc[i][j], 0, 0, 0);
  }

  #pragma unroll
  for (int i = 0; i < FM; ++i) {
    #pragma unroll
    for (int j = 0; j < FN; ++j) {
      #pragma unroll
      for (int r = 0; r < 4; ++r) {
        int grow = m0 + wm + i * 16 + quad * 4 + r;
        int gcol = n0 + wn + j * 16 + md;
        int bb = grow >> 10, s = grow & (SEQ - 1);
        int h = gcol >> 6, dk = gcol & (DH - 1);
        float vb = acc[i][j][r] + bias[gcol];
        if (z < 2)
          o[(((long long)(bb * NH + h)) * SEQ + s) * DH + dk] = f2bf(vb);
        else
          o[(((long long)(bb * NH + h)) * DH + dk) * SEQ + s] = f2bf(vb);
      }
    }
  }
}

// Fused attention: scores -> online softmax -> normalized attn write -> P@V.
// v3 = v1 structure (32 q-rows/wave, 768 blocks, NONTEMPORAL attn stores so
// the 384MB stream neither RMW-fetches lines nor evicts K/V from L2 — v2
// showed plain stores cause exactly that: FETCH 278MB, all pipes idle)
// + exp2-domain softmax + vectorized attn stores: P is already staged in LDS
// for PV, so read it back transposed (lane = row/col-half) and emit float4
// NT stores (1KB/wave-instr, 4x fewer store instructions than scalar).
__global__ __launch_bounds__(256, 2)
void attn_fused(const u16* __restrict__ Qh, const u16* __restrict__ Kh,
                const u16* __restrict__ VT, const float* __restrict__ mask,
                float* __restrict__ attn, u16* __restrict__ ctx)
{
  __shared__ u16 Plds[4 * 32 * 128];   // 32 KB, 8 KB per wave
  const int tid = threadIdx.x;
  const int w = tid >> 6, l = tid & 63;
  const int quad = l >> 4, md = l & 15;
  constexpr float SC2 = 0.125f * 1.4426950408889634f;     // 1/8 * log2(e)
  constexpr float MSK2 = -10000.0f * 1.4426950408889634f; // mask penalty, log2 dom
  // XCD-bijective swizzle: 768 blocks = 96 per XCD; one XCD owns 12 whole
  // heads so K/V (256 KB/head) stay resident in that XCD's L2.
  const int dsp = blockIdx.x;
  const int L = (dsp & 7) * 96 + (dsp >> 3);
  const int bh = L >> 3, rb = L & 7;
  const int b = bh / NH, h = bh - b * NH;
  const int m0 = rb * 128;
  const int wm = w * 32;

  const u16* Qb = Qh + (long long)bh * SEQ * DH;
  const u16* Kb = Kh + (long long)bh * SEQ * DH;
  const u16* Vb = VT + (long long)bh * DH * SEQ;
  const float* mrow = mask + b * SEQ;
  float* arow = attn + (long long)bh * SEQ * SEQ;

  // Q A-fragments, persistent: row = m0+wm+i*16+md, k = kk*32+quad*8 (16B)
  bf16x8 aq[2][2];
  #pragma unroll
  for (int i = 0; i < 2; ++i)
    #pragma unroll
    for (int kk = 0; kk < 2; ++kk)
      aq[i][kk] = *(const bf16x8*)(Qb + (long long)(m0 + wm + i * 16 + md) * DH + kk * 32 + quad * 8);

  float m_run[2][4], s_run[2][4];
  #pragma unroll
  for (int i = 0; i < 2; ++i)
    #pragma unroll
    for (int r = 0; r < 4; ++r) { m_run[i][r] = -3.0e38f; s_run[i][r] = 0.0f; }

  f32x4 zero = {0.f, 0.f, 0.f, 0.f};

  // ---------- pass 1: online row max / sum in exp2 domain (no writes) ----------
  for (int t = 0; t < 8; ++t) {
    const int n0 = t * 128;
    float madd2[8];
    #pragma unroll
    for (int j = 0; j < 8; ++j)
      madd2[j] = (1.0f - mrow[n0 + j * 16 + md]) * MSK2;
    f32x4 acc[2][8];
    #pragma unroll
    for (int i = 0; i < 2; ++i)
      #pragma unroll
      for (int j = 0; j < 8; ++j) acc[i][j] = zero;
    #pragma unroll
    for (int j = 0; j < 8; ++j) {
      const u16* kp = Kb + (long long)(n0 + j * 16 + md) * DH + quad * 8;
      bf16x8 b0 = *(const bf16x8*)kp;
      bf16x8 b1 = *(const bf16x8*)(kp + 32);
      #pragma unroll
      for (int i = 0; i < 2; ++i) {
        acc[i][j] = __builtin_amdgcn_mfma_f32_16x16x32_bf16(aq[i][0], b0, acc[i][j], 0, 0, 0);
        acc[i][j] = __builtin_amdgcn_mfma_f32_16x16x32_bf16(aq[i][1], b1, acc[i][j], 0, 0, 0);
      }
    }
    #pragma unroll
    for (int i = 0; i < 2; ++i) {
      #pragma unroll
      for (int r = 0; r < 4; ++r) {
        float sc[8];
        float tm = -3.0e38f;
        #pragma unroll
        for (int j = 0; j < 8; ++j) {
          sc[j] = acc[i][j][r] * SC2 + madd2[j];
          tm = fmaxf(tm, sc[j]);
        }
        #pragma unroll
        for (int s = 1; s < 16; s <<= 1) tm = fmaxf(tm, __shfl_xor(tm, s, 64));
        float mn = fmaxf(m_run[i][r], tm);
        float ps = 0.0f;
        #pragma unroll
        for (int j = 0; j < 8; ++j) ps += fexp2(sc[j] - mn);
        #pragma unroll
        for (int s = 1; s < 16; s <<= 1) ps += __shfl_xor(ps, s, 64);
        s_run[i][r] = s_run[i][r] * fexp2(m_run[i][r] - mn) + ps;
        m_run[i][r] = mn;
      }
    }
  }
  float inv_s[2][4];
  #pragma unroll
  for (int i = 0; i < 2; ++i)
    #pragma unroll
    for (int r = 0; r < 4; ++r) inv_s[i][r] = 1.0f / s_run[i][r];

  // ---------- pass 2: recompute, stage P in LDS, NT-write attn, P@V ----------
  f32x4 cacc[2][4];
  #pragma unroll
  for (int i = 0; i < 2; ++i)
    #pragma unroll
    for (int jd = 0; jd < 4; ++jd) cacc[i][jd] = zero;
  char* Pw = (char*)Plds + w * 8192;   // wave-private 32x128 bf16 region
  const int srl = l >> 1, sch = l & 1; // store role: row, 64-col half
  float* gp0 = arow + (long long)(m0 + wm + srl) * SEQ + sch * 64;

  for (int t = 0; t < 8; ++t) {
    const int n0 = t * 128;
    float madd2[8];
    #pragma unroll
    for (int j = 0; j < 8; ++j)
      madd2[j] = (1.0f - mrow[n0 + j * 16 + md]) * MSK2;
    f32x4 acc[2][8];
    #pragma unroll
    for (int i = 0; i < 2; ++i)
      #pragma unroll
      for (int j = 0; j < 8; ++j) acc[i][j] = zero;
    #pragma unroll
    for (int j = 0; j < 8; ++j) {
      const u16* kp = Kb + (long long)(n0 + j * 16 + md) * DH + quad * 8;
      bf16x8 b0 = *(const bf16x8*)kp;
      bf16x8 b1 = *(const bf16x8*)(kp + 32);
      #pragma unroll
      for (int i = 0; i < 2; ++i) {
        acc[i][j] = __builtin_amdgcn_mfma_f32_16x16x32_bf16(aq[i][0], b0, acc[i][j], 0, 0, 0);
        acc[i][j] = __builtin_amdgcn_mfma_f32_16x16x32_bf16(aq[i][1], b1, acc[i][j], 0, 0, 0);
      }
    }
    // normalize + stage bf16 P into swizzled LDS (write is conflict-free:
    // quads land in disjoint bank groups via (rl&7)<<4 ^ (rl&8)<<2).
    #pragma unroll
    for (int i = 0; i < 2; ++i) {
      #pragma unroll
      for (int j = 0; j < 8; ++j) {
        #pragma unroll
        for (int r = 0; r < 4; ++r) {
          float p = fexp2(acc[i][j][r] * SC2 + madd2[j] - m_run[i][r]) * inv_s[i][r];
          int rl = i * 16 + quad * 4 + r;
          int byo = (rl * 256 + (j * 16 + md) * 2) ^ ((rl & 7) << 4) ^ ((rl & 8) << 2);
          *(u16*)(Pw + byo) = f2bf(p);
        }
      }
    }
    // vectorized attn write: lane srl/sch reads its contiguous row segment
    // back from LDS (2-way banked = free) and NT-stores float4s (full lines,
    // no L2 pollution -> K/V stay resident).
    {
      float* gp = gp0 + n0;
      #pragma unroll
      for (int g = 0; g < 8; ++g) {
        int byo = (srl * 256 + (sch * 64 + g * 8) * 2) ^ ((srl & 7) << 4) ^ ((srl & 8) << 2);
        u16x8 pk = *(const u16x8*)(Pw + byo);
        f32x4 o0, o1;
        #pragma unroll
        for (int e = 0; e < 4; ++e) o0[e] = bf2f(pk[e]);
        #pragma unroll
        for (int e = 0; e < 4; ++e) o1[e] = bf2f(pk[4 + e]);
        __builtin_nontemporal_store(o0, (f32x4*)(gp + g * 8));
        __builtin_nontemporal_store(o1, (f32x4*)(gp + g * 8 + 4));
      }
    }
    // P@V: A = P from LDS (swizzled read), B = VT direct from global (L2-hot).
    #pragma unroll
    for (int kk2 = 0; kk2 < 4; ++kk2) {
      bf16x8 ap[2];
      #pragma unroll
      for (int i = 0; i < 2; ++i) {
        int rl = i * 16 + md;
        int byo = (rl * 256 + (kk2 * 32 + quad * 8) * 2) ^ ((rl & 7) << 4) ^ ((rl & 8) << 2);
        ap[i] = *(const bf16x8*)(Pw + byo);
      }
      #pragma unroll
      for (int jd = 0; jd < 4; ++jd) {
        bf16x8 bv = *(const bf16x8*)(Vb + (long long)(jd * 16 + md) * SEQ + n0 + kk2 * 32 + quad * 8);
        cacc[0][jd] = __builtin_amdgcn_mfma_f32_16x16x32_bf16(ap[0], bv, cacc[0][jd], 0, 0, 0);
        cacc[1][jd] = __builtin_amdgcn_mfma_f32_16x16x32_bf16(ap[1], bv, cacc[1][jd], 0, 0, 0);
      }
    }
  }

  // epilogue: ctx bf16, merged-head layout [B,S,H,DH] == [TOK, DM]
  #pragma unroll
  for (int i = 0; i < 2; ++i) {
    #pragma unroll
    for (int jd = 0; jd < 4; ++jd) {
      #pragma unroll
      for (int r = 0; r < 4; ++r) {
        int grow = m0 + wm + i * 16 + quad * 4 + r;
        ctx[((long long)(b * SEQ + grow)) * DM + h * DH + jd * 16 + md] = f2bf(cacc[i][jd][r]);
      }
    }
  }
}

// fp32 LayerNorm over 768; one wave per row, 4 rows/block
__global__ __launch_bounds__(256) void layernorm_rows(const float* __restrict__ x,
    const float* __restrict__ gamma, const float* __restrict__ beta,
    float* __restrict__ out) {
  const int w = threadIdx.x >> 6, l = threadIdx.x & 63;
  const long long row = (long long)blockIdx.x * 4 + w;
  const float* px = x + row * DM;
  float v[12];
  float sum = 0.f;
  #pragma unroll
  for (int c = 0; c < 3; ++c) {
    float4 f = *(const float4*)&px[c * 256 + l * 4];
    v[c*4+0] = f.x; v[c*4+1] = f.y; v[c*4+2] = f.z; v[c*4+3] = f.w;
    sum += f.x + f.y + f.z + f.w;
  }
  #pragma unroll
  for (int s = 1; s < 64; s <<= 1) sum += __shfl_xor(sum, s, 64);
  float mu = sum * (1.0f / 768.0f);
  float s2 = 0.f;
  #pragma unroll
  for (int e = 0; e < 12; ++e) { float d = v[e] - mu; s2 += d * d; }
  #pragma unroll
  for (int s = 1; s < 64; s <<= 1) s2 += __shfl_xor(s2, s, 64);
  float rs = rsqrtf(s2 * (1.0f / 768.0f) + 1e-8f);
  #pragma unroll
  for (int c = 0; c < 3; ++c) {
    float4 o;
    #pragma unroll
    for (int e = 0; e < 4; ++e) {
      int col = c * 256 + l * 4 + e;
      ((float*)&o)[e] = (v[c*4+e] - mu) * rs * gamma[col] + beta[col];
    }
    *(float4*)&out[row * DM + c * 256 + l * 4] = o;
  }
}

// cast fp32 [768,768] weights -> bf16 transposed, 4 weights via z
__global__ __launch_bounds__(256) void castT_w(
    const float* __restrict__ W0, const float* __restrict__ W1,
    const float* __restrict__ W2, const float* __restrict__ W3,
    u16* __restrict__ Tbase) {
  __shared__ u16 t[64][65];
  const int z = blockIdx.z;
  const float* W = z == 0 ? W0 : z == 1 ? W1 : z == 2 ? W2 : W3;
  u16* T = Tbase + (long long)z * DM * DM;
  const int bx = blockIdx.x, by = blockIdx.y;
  #pragma unroll
  for (int it = 0; it < 16; ++it) {
    int idx = it * 256 + (int)threadIdx.x;
    int r = idx >> 6, c = idx & 63;
    t[r][c] = f2bf(W[(long long)(by * 64 + r) * DM + bx * 64 + c]);
  }
  __syncthreads();
  #pragma unroll
  for (int it = 0; it < 16; ++it) {
    int idx = it * 256 + (int)threadIdx.x;
    int r = idx >> 6, c = idx & 63;
    T[(long long)(bx * 64 + r) * DM + by * 64 + c] = t[c][r];
  }
}

// cast q/k/v fp32 -> bf16 contiguous, z selects tensor; 8 elems/thread
__global__ __launch_bounds__(256) void cast3_bf16(
    const float* __restrict__ q, const float* __restrict__ k,
    const float* __restrict__ v, u16* __restrict__ dst) {
  const int z = blockIdx.z;
  const float* src = z == 0 ? q : z == 1 ? k : v;
  u16* d = dst + (long long)z * NB * SEQ * DM;
  long long i = ((long long)blockIdx.x * 256 + threadIdx.x) * 8;
  float4 f0 = *(const float4*)&src[i];
  float4 f1 = *(const float4*)&src[i + 4];
  u16x8 o;
  o[0] = f2bf(f0.x); o[1] = f2bf(f0.y); o[2] = f2bf(f0.z); o[3] = f2bf(f0.w);
  o[4] = f2bf(f1.x); o[5] = f2bf(f1.y); o[6] = f2bf(f1.z); o[7] = f2bf(f1.w);
  *(u16x8*)&d[i] = o;
}

extern "C" void kernel_launch(void* const* d_in, const int* in_sizes, int n_in,
                              void* d_out, int out_size, void* d_ws, size_t ws_size,
                              hipStream_t stream) {
  const float* query = (const float*)d_in[0];
  const float* key   = (const float*)d_in[1];
  const float* value = (const float*)d_in[2];
  const float* mask  = (const float*)d_in[3];
  const float* Wq = (const float*)d_in[4];
  const float* bq = (const float*)d_in[5];
  const float* Wk = (const float*)d_in[6];
  const float* bk = (const float*)d_in[7];
  const float* Wv = (const float*)d_in[8];
  const float* bv = (const float*)d_in[9];
  const float* Wo = (const float*)d_in[10];
  const float* bo = (const float*)d_in[11];
  const float* gamma = (const float*)d_in[12];
  const float* beta  = (const float*)d_in[13];

  const long long TOK = (long long)NB * SEQ;        // 8192
  float* out  = (float*)d_out;                      // [TOK, DM] fp32
  float* attn = out + TOK * DM;                     // [NB,NH,SEQ,SEQ] fp32

  // ws: 3 bf16 slots of TOK*DM (37.75 MB total)
  u16* s0 = (u16*)d_ws;            // Qh [B,H,S,DH]
  u16* s1 = s0 + TOK * DM;         // Kh [B,H,S,DH] -> later X fp32 (s1+s2)
  u16* s2 = s1 + TOK * DM;         // VT [B,H,DH,S]
  float* X = (float*)s1;           // [TOK, DM] fp32 == s1..s2 exactly

  // scratch in dead d_out regions:
  u16* WqT = (u16*)d_out;          // out region dead until final LN
  u16* WoT = WqT + 3 * (long long)DM * DM;
  u16* ctx = WqT + 4 * (long long)DM * DM;  // bf16 [TOK,DM], 12.6 MB, fits
  u16* qB = (u16*)attn;            // attn region dead until attn_fused writes

  // 1) weights -> bf16 transposed (WqT, WkT, WvT, WoT contiguous)
  castT_w<<<dim3(12, 12, 4), 256, 0, stream>>>(Wq, Wk, Wv, Wo, WqT);
  // 2) q,k,v -> bf16 (in attn-region scratch)
  cast3_bf16<<<dim3(3072, 1, 3), 256, 0, stream>>>(query, key, value, qB);

  // 3) merged QKV projections: M=8192, N=768, K=768, z over {Q,K,V}
  gemm_qkv<<<dim3(64, 6, 3), 256, 0, stream>>>(qB, WqT, bq, bk, bv, s0);

  // 4) fused attention: scores + softmax + attn-write + P@V in one kernel.
  attn_fused<<<dim3(768, 1, 1), 256, 0, stream>>>(s0, s1, s2, mask, attn, ctx);

  // 5) out projection + bias + residual -> X fp32 (Kh,VT dead)
  gemm_bt<128,128,4><<<dim3(64, 6, 1), 256, 0, stream>>>(
      ctx, DM, 0, WoT, DM, 0, bo, query, X, DM);

  // 6) LayerNorm -> out (overwrites WqT../ctx scratch, now dead)
  layernorm_rows<<<(int)(TOK / 4), 256, 0, stream>>>(X, gamma, beta, out);
}

// Round 4
// 714.987 us; speedup vs baseline: 2.2949x; 2.2949x over previous
//
#include <hip/hip_runtime.h>
#include <cstdint>

typedef unsigned short u16;
typedef __attribute__((ext_vector_type(8))) short bf16x8;
typedef __attribute__((ext_vector_type(4))) float f32x4;
typedef __attribute__((ext_vector_type(8))) unsigned short u16x8;

constexpr int NB = 8;       // batch
constexpr int SEQ = 1024;   // sequence
constexpr int NH = 12;      // heads
constexpr int DM = 768;     // model dim
constexpr int DH = 64;      // head dim

__device__ __forceinline__ u16 f2bf(float f) {
  unsigned int x = __builtin_bit_cast(unsigned int, f);
  x += 0x7fffu + ((x >> 16) & 1u);
  return (u16)(x >> 16);
}

#if __has_builtin(__builtin_amdgcn_exp2f)
__device__ __forceinline__ float fexp2(float x) { return __builtin_amdgcn_exp2f(x); }
#else
__device__ __forceinline__ float fexp2(float x) { return exp2f(x); }
#endif

typedef __attribute__((address_space(1))) void* as1vp;
typedef __attribute__((address_space(3))) void* as3vp;

__device__ __forceinline__ void load_lds16(const u16* g, u16* l) {
  __builtin_amdgcn_global_load_lds((as1vp)(g), (as3vp)(l), 16, 0, 0);
}

// C = A @ B. A [M,K] row-major bf16 (lda), B TRANSPOSED: BT [N,K] bf16 (ldb).
// 16x16x32 bf16 MFMA, TM x TN tile, BK=32, 256 threads (2x2 waves).
//  EPI 4: out proj -> FP32 [TOK,DM], + fp32 bias + fp32 residual
template<int TM, int TN, int EPI>
__global__ __launch_bounds__(256)
void gemm_bt(const u16* __restrict__ A, int lda, long long strideA,
             const u16* __restrict__ BT, int ldb, long long strideBT,
             const float* __restrict__ bias,
             const float* __restrict__ extra,
             void* __restrict__ outp,
             int K)
{
  constexpr int BK = 32;
  constexpr int WM = TM / 2, WN = TN / 2;
  constexpr int FM = WM / 16, FN = WN / 16;
  __shared__ u16 As[TM * BK];
  __shared__ u16 Bs[TN * BK];
  const int tid = threadIdx.x;
  const int w = tid >> 6, l = tid & 63;
  const int z = blockIdx.z;
  const u16* Az = A + (long long)z * strideA;
  const u16* Bz = BT + (long long)z * strideBT;
  const int m0 = blockIdx.x * TM, n0 = blockIdx.y * TN;
  const int wm = (w & 1) * WM, wn = (w >> 1) * WN;
  const int quad = l >> 4, md = l & 15;

  f32x4 acc[FM][FN];
  f32x4 zero = {0.f, 0.f, 0.f, 0.f};
  #pragma unroll
  for (int i = 0; i < FM; ++i)
    #pragma unroll
    for (int j = 0; j < FN; ++j) acc[i][j] = zero;

  for (int k0 = 0; k0 < K; k0 += BK) {
    __syncthreads();
    #pragma unroll
    for (int r = 0; r < TM / 64; ++r) {
      int lin = r * 256 + tid;
      int row = lin >> 2, ch = lin & 3;
      load_lds16(Az + (long long)(m0 + row) * lda + k0 + ch * 8, &As[lin * 8]);
    }
    #pragma unroll
    for (int r = 0; r < TN / 64; ++r) {
      int lin = r * 256 + tid;
      int row = lin >> 2, ch = lin & 3;
      load_lds16(Bz + (long long)(n0 + row) * ldb + k0 + ch * 8, &Bs[lin * 8]);
    }
    __syncthreads();
    bf16x8 af[FM], bfr[FN];
    #pragma unroll
    for (int i = 0; i < FM; ++i)
      af[i] = *(const bf16x8*)&As[(wm + i * 16 + md) * BK + quad * 8];
    #pragma unroll
    for (int j = 0; j < FN; ++j)
      bfr[j] = *(const bf16x8*)&Bs[(wn + j * 16 + md) * BK + quad * 8];
    #pragma unroll
    for (int i = 0; i < FM; ++i)
      #pragma unroll
      for (int j = 0; j < FN; ++j)
        acc[i][j] = __builtin_amdgcn_mfma_f32_16x16x32_bf16(af[i], bfr[j], acc[i][j], 0, 0, 0);
  }

  #pragma unroll
  for (int i = 0; i < FM; ++i) {
    #pragma unroll
    for (int j = 0; j < FN; ++j) {
      #pragma unroll
      for (int r = 0; r < 4; ++r) {
        int grow = m0 + wm + i * 16 + quad * 4 + r;
        int gcol = n0 + wn + j * 16 + md;
        float v = acc[i][j][r];
        float vv = v + bias[gcol] + extra[(long long)grow * DM + gcol];
        ((float*)outp)[(long long)grow * DM + gcol] = vv;
      }
    }
  }
}

// Merged QKV projection: grid (64, 6, 3); z=0 Q, z=1 K (head-split layout),
// z=2 V (transposed [B,H,DH,S] layout). A slots and W slots contiguous.
__global__ __launch_bounds__(256)
void gemm_qkv(const u16* __restrict__ Abase, const u16* __restrict__ Wbase,
              const float* __restrict__ bq, const float* __restrict__ bk,
              const float* __restrict__ bv, u16* __restrict__ outbase)
{
  constexpr int TM = 128, TN = 128, BK = 32;
  constexpr int WM = 64, WN = 64, FM = 4, FN = 4;
  __shared__ u16 As[TM * BK];
  __shared__ u16 Bs[TN * BK];
  const int tid = threadIdx.x;
  const int w = tid >> 6, l = tid & 63;
  const int z = blockIdx.z;
  const long long TOKDM = (long long)NB * SEQ * DM;
  const u16* Az = Abase + (long long)z * TOKDM;
  const u16* Bz = Wbase + (long long)z * DM * DM;
  const float* bias = z == 0 ? bq : z == 1 ? bk : bv;
  u16* o = outbase + (long long)z * TOKDM;
  const int m0 = blockIdx.x * TM, n0 = blockIdx.y * TN;
  const int wm = (w & 1) * WM, wn = (w >> 1) * WN;
  const int quad = l >> 4, md = l & 15;

  f32x4 acc[FM][FN];
  f32x4 zero = {0.f, 0.f, 0.f, 0.f};
  #pragma unroll
  for (int i = 0; i < FM; ++i)
    #pragma unroll
    for (int j = 0; j < FN; ++j) acc[i][j] = zero;

  for (int k0 = 0; k0 < DM; k0 += BK) {
    __syncthreads();
    #pragma unroll
    for (int r = 0; r < 2; ++r) {
      int lin = r * 256 + tid;
      int row = lin >> 2, ch = lin & 3;
      load_lds16(Az + (long long)(m0 + row) * DM + k0 + ch * 8, &As[lin * 8]);
    }
    #pragma unroll
    for (int r = 0; r < 2; ++r) {
      int lin = r * 256 + tid;
      int row = lin >> 2, ch = lin & 3;
      load_lds16(Bz + (long long)(n0 + row) * DM + k0 + ch * 8, &Bs[lin * 8]);
    }
    __syncthreads();
    bf16x8 af[FM], bfr[FN];
    #pragma unroll
    for (int i = 0; i < FM; ++i)
      af[i] = *(const bf16x8*)&As[(wm + i * 16 + md) * BK + quad * 8];
    #pragma unroll
    for (int j = 0; j < FN; ++j)
      bfr[j] = *(const bf16x8*)&Bs[(wn + j * 16 + md) * BK + quad * 8];
    #pragma unroll
    for (int i = 0; i < FM; ++i)
      #pragma unroll
      for (int j = 0; j < FN; ++j)
        acc[i][j] = __builtin_amdgcn_mfma_f32_16x16x32_bf16(af[i], bfr[j], acc[i][j], 0, 0, 0);
  }

  #pragma unroll
  for (int i = 0; i < FM; ++i) {
    #pragma unroll
    for (int j = 0; j < FN; ++j) {
      #pragma unroll
      for (int r = 0; r < 4; ++r) {
        int grow = m0 + wm + i * 16 + quad * 4 + r;
        int gcol = n0 + wn + j * 16 + md;
        int bb = grow >> 10, s = grow & (SEQ - 1);
        int h = gcol >> 6, dk = gcol & (DH - 1);
        float vb = acc[i][j][r] + bias[gcol];
        if (z < 2)
          o[(((long long)(bb * NH + h)) * SEQ + s) * DH + dk] = f2bf(vb);
        else
          o[(((long long)(bb * NH + h)) * DH + dk) * SEQ + s] = f2bf(vb);
      }
    }
  }
}

// Fused attention: scores -> online softmax -> normalized attn write -> P@V.
// v4 = v1 memory structure exactly (32 q-rows/wave, 768 blocks, SCALAR
// NONTEMPORAL attn stores from registers — each wave instr covers 4 rows x
// 64B contiguous, and the j-loop completes each 128B line promptly, so the
// WC path emits full lines; v3's lane-per-row f32x4 NT variant fragmented
// 64 lines/instr -> 3x write amplification, 1.2GB, 1135us).
// Register-level improvements kept: exp2-domain softmax; pass-1 sum reduce
// deferred to per-lane partials (one final shfl reduce instead of per-tile:
// 256 -> 32 ds_bpermute/lane); conflict-free P-staging XOR.
__global__ __launch_bounds__(256, 2)
void attn_fused(const u16* __restrict__ Qh, const u16* __restrict__ Kh,
                const u16* __restrict__ VT, const float* __restrict__ mask,
                float* __restrict__ attn, u16* __restrict__ ctx)
{
  __shared__ u16 Plds[4 * 32 * 128];   // 32 KB, 8 KB per wave
  const int tid = threadIdx.x;
  const int w = tid >> 6, l = tid & 63;
  const int quad = l >> 4, md = l & 15;
  constexpr float SC2 = 0.125f * 1.4426950408889634f;     // 1/8 * log2(e)
  constexpr float MSK2 = -10000.0f * 1.4426950408889634f; // mask penalty, log2 dom
  // XCD-bijective swizzle: 768 blocks = 96 per XCD; one XCD owns 12 whole
  // heads so K/V (256 KB/head) stay resident in that XCD's L2.
  const int dsp = blockIdx.x;
  const int L = (dsp & 7) * 96 + (dsp >> 3);
  const int bh = L >> 3, rb = L & 7;
  const int b = bh / NH, h = bh - b * NH;
  const int m0 = rb * 128;
  const int wm = w * 32;

  const u16* Qb = Qh + (long long)bh * SEQ * DH;
  const u16* Kb = Kh + (long long)bh * SEQ * DH;
  const u16* Vb = VT + (long long)bh * DH * SEQ;
  const float* mrow = mask + b * SEQ;
  float* arow = attn + (long long)bh * SEQ * SEQ;

  // Q A-fragments, persistent: row = m0+wm+i*16+md, k = kk*32+quad*8 (16B)
  bf16x8 aq[2][2];
  #pragma unroll
  for (int i = 0; i < 2; ++i)
    #pragma unroll
    for (int kk = 0; kk < 2; ++kk)
      aq[i][kk] = *(const bf16x8*)(Qb + (long long)(m0 + wm + i * 16 + md) * DH + kk * 32 + quad * 8);

  float m_run[2][4], s_part[2][4];
  #pragma unroll
  for (int i = 0; i < 2; ++i)
    #pragma unroll
    for (int r = 0; r < 4; ++r) { m_run[i][r] = -3.0e38f; s_part[i][r] = 0.0f; }

  f32x4 zero = {0.f, 0.f, 0.f, 0.f};

  // ---------- pass 1: online row max + per-lane partial sums (no writes) ----------
  for (int t = 0; t < 8; ++t) {
    const int n0 = t * 128;
    float madd2[8];
    #pragma unroll
    for (int j = 0; j < 8; ++j)
      madd2[j] = (1.0f - mrow[n0 + j * 16 + md]) * MSK2;
    f32x4 acc[2][8];
    #pragma unroll
    for (int i = 0; i < 2; ++i)
      #pragma unroll
      for (int j = 0; j < 8; ++j) acc[i][j] = zero;
    #pragma unroll
    for (int j = 0; j < 8; ++j) {
      const u16* kp = Kb + (long long)(n0 + j * 16 + md) * DH + quad * 8;
      bf16x8 b0 = *(const bf16x8*)kp;
      bf16x8 b1 = *(const bf16x8*)(kp + 32);
      #pragma unroll
      for (int i = 0; i < 2; ++i) {
        acc[i][j] = __builtin_amdgcn_mfma_f32_16x16x32_bf16(aq[i][0], b0, acc[i][j], 0, 0, 0);
        acc[i][j] = __builtin_amdgcn_mfma_f32_16x16x32_bf16(aq[i][1], b1, acc[i][j], 0, 0, 0);
      }
    }
    #pragma unroll
    for (int i = 0; i < 2; ++i) {
      #pragma unroll
      for (int r = 0; r < 4; ++r) {
        float sc[8];
        float tm = -3.0e38f;
        #pragma unroll
        for (int j = 0; j < 8; ++j) {
          sc[j] = acc[i][j][r] * SC2 + madd2[j];
          tm = fmaxf(tm, sc[j]);
        }
        #pragma unroll
        for (int s = 1; s < 16; s <<= 1) tm = fmaxf(tm, __shfl_xor(tm, s, 64));
        float mn = fmaxf(m_run[i][r], tm);
        float ps = 0.0f;
        #pragma unroll
        for (int j = 0; j < 8; ++j) ps += fexp2(sc[j] - mn);
        // per-lane partial, rescaled; reduced across lanes ONCE after the loop
        s_part[i][r] = s_part[i][r] * fexp2(m_run[i][r] - mn) + ps;
        m_run[i][r] = mn;
      }
    }
  }
  float inv_s[2][4];
  #pragma unroll
  for (int i = 0; i < 2; ++i)
    #pragma unroll
    for (int r = 0; r < 4; ++r) {
      float s_tot = s_part[i][r];
      #pragma unroll
      for (int s = 1; s < 16; s <<= 1) s_tot += __shfl_xor(s_tot, s, 64);
      inv_s[i][r] = 1.0f / s_tot;
    }

  // ---------- pass 2: recompute, NT-write attn, stage P, P@V ----------
  f32x4 cacc[2][4];
  #pragma unroll
  for (int i = 0; i < 2; ++i)
    #pragma unroll
    for (int jd = 0; jd < 4; ++jd) cacc[i][jd] = zero;
  char* Pw = (char*)Plds + w * 8192;   // wave-private 32x128 bf16 region

  for (int t = 0; t < 8; ++t) {
    const int n0 = t * 128;
    float madd2[8];
    #pragma unroll
    for (int j = 0; j < 8; ++j)
      madd2[j] = (1.0f - mrow[n0 + j * 16 + md]) * MSK2;
    f32x4 acc[2][8];
    #pragma unroll
    for (int i = 0; i < 2; ++i)
      #pragma unroll
      for (int j = 0; j < 8; ++j) acc[i][j] = zero;
    #pragma unroll
    for (int j = 0; j < 8; ++j) {
      const u16* kp = Kb + (long long)(n0 + j * 16 + md) * DH + quad * 8;
      bf16x8 b0 = *(const bf16x8*)kp;
      bf16x8 b1 = *(const bf16x8*)(kp + 32);
      #pragma unroll
      for (int i = 0; i < 2; ++i) {
        acc[i][j] = __builtin_amdgcn_mfma_f32_16x16x32_bf16(aq[i][0], b0, acc[i][j], 0, 0, 0);
        acc[i][j] = __builtin_amdgcn_mfma_f32_16x16x32_bf16(aq[i][1], b1, acc[i][j], 0, 0, 0);
      }
    }
    // normalize, NT-write attn (scalar, 4rows x 64B/instr, line-friendly),
    // stage bf16 P into conflict-free swizzled LDS.
    #pragma unroll
    for (int i = 0; i < 2; ++i) {
      #pragma unroll
      for (int j = 0; j < 8; ++j) {
        #pragma unroll
        for (int r = 0; r < 4; ++r) {
          float p = fexp2(acc[i][j][r] * SC2 + madd2[j] - m_run[i][r]) * inv_s[i][r];
          int grow = m0 + wm + i * 16 + quad * 4 + r;
          __builtin_nontemporal_store(p, &arow[(long long)grow * SEQ + n0 + j * 16 + md]);
          int rl = i * 16 + quad * 4 + r;
          int byo = (rl * 256 + (j * 16 + md) * 2) ^ ((rl & 7) << 4) ^ ((rl & 8) << 2);
          *(u16*)(Pw + byo) = f2bf(p);
        }
      }
    }
    // P@V: A = P from LDS (swizzled read), B = VT direct from global (L2-hot).
    #pragma unroll
    for (int kk2 = 0; kk2 < 4; ++kk2) {
      bf16x8 ap[2];
      #pragma unroll
      for (int i = 0; i < 2; ++i) {
        int rl = i * 16 + md;
        int byo = (rl * 256 + (kk2 * 32 + quad * 8) * 2) ^ ((rl & 7) << 4) ^ ((rl & 8) << 2);
        ap[i] = *(const bf16x8*)(Pw + byo);
      }
      #pragma unroll
      for (int jd = 0; jd < 4; ++jd) {
        bf16x8 bv = *(const bf16x8*)(Vb + (long long)(jd * 16 + md) * SEQ + n0 + kk2 * 32 + quad * 8);
        cacc[0][jd] = __builtin_amdgcn_mfma_f32_16x16x32_bf16(ap[0], bv, cacc[0][jd], 0, 0, 0);
        cacc[1][jd] = __builtin_amdgcn_mfma_f32_16x16x32_bf16(ap[1], bv, cacc[1][jd], 0, 0, 0);
      }
    }
  }

  // epilogue: ctx bf16, merged-head layout [B,S,H,DH] == [TOK, DM]
  #pragma unroll
  for (int i = 0; i < 2; ++i) {
    #pragma unroll
    for (int jd = 0; jd < 4; ++jd) {
      #pragma unroll
      for (int r = 0; r < 4; ++r) {
        int grow = m0 + wm + i * 16 + quad * 4 + r;
        ctx[((long long)(b * SEQ + grow)) * DM + h * DH + jd * 16 + md] = f2bf(cacc[i][jd][r]);
      }
    }
  }
}

// fp32 LayerNorm over 768; one wave per row, 4 rows/block
__global__ __launch_bounds__(256) void layernorm_rows(const float* __restrict__ x,
    const float* __restrict__ gamma, const float* __restrict__ beta,
    float* __restrict__ out) {
  const int w = threadIdx.x >> 6, l = threadIdx.x & 63;
  const long long row = (long long)blockIdx.x * 4 + w;
  const float* px = x + row * DM;
  float v[12];
  float sum = 0.f;
  #pragma unroll
  for (int c = 0; c < 3; ++c) {
    float4 f = *(const float4*)&px[c * 256 + l * 4];
    v[c*4+0] = f.x; v[c*4+1] = f.y; v[c*4+2] = f.z; v[c*4+3] = f.w;
    sum += f.x + f.y + f.z + f.w;
  }
  #pragma unroll
  for (int s = 1; s < 64; s <<= 1) sum += __shfl_xor(sum, s, 64);
  float mu = sum * (1.0f / 768.0f);
  float s2 = 0.f;
  #pragma unroll
  for (int e = 0; e < 12; ++e) { float d = v[e] - mu; s2 += d * d; }
  #pragma unroll
  for (int s = 1; s < 64; s <<= 1) s2 += __shfl_xor(s2, s, 64);
  float rs = rsqrtf(s2 * (1.0f / 768.0f) + 1e-8f);
  #pragma unroll
  for (int c = 0; c < 3; ++c) {
    float4 o;
    #pragma unroll
    for (int e = 0; e < 4; ++e) {
      int col = c * 256 + l * 4 + e;
      ((float*)&o)[e] = (v[c*4+e] - mu) * rs * gamma[col] + beta[col];
    }
    *(float4*)&out[row * DM + c * 256 + l * 4] = o;
  }
}

// cast fp32 [768,768] weights -> bf16 transposed, 4 weights via z
__global__ __launch_bounds__(256) void castT_w(
    const float* __restrict__ W0, const float* __restrict__ W1,
    const float* __restrict__ W2, const float* __restrict__ W3,
    u16* __restrict__ Tbase) {
  __shared__ u16 t[64][65];
  const int z = blockIdx.z;
  const float* W = z == 0 ? W0 : z == 1 ? W1 : z == 2 ? W2 : W3;
  u16* T = Tbase + (long long)z * DM * DM;
  const int bx = blockIdx.x, by = blockIdx.y;
  #pragma unroll
  for (int it = 0; it < 16; ++it) {
    int idx = it * 256 + (int)threadIdx.x;
    int r = idx >> 6, c = idx & 63;
    t[r][c] = f2bf(W[(long long)(by * 64 + r) * DM + bx * 64 + c]);
  }
  __syncthreads();
  #pragma unroll
  for (int it = 0; it < 16; ++it) {
    int idx = it * 256 + (int)threadIdx.x;
    int r = idx >> 6, c = idx & 63;
    T[(long long)(bx * 64 + r) * DM + by * 64 + c] = t[c][r];
  }
}

// cast q/k/v fp32 -> bf16 contiguous, z selects tensor; 8 elems/thread
__global__ __launch_bounds__(256) void cast3_bf16(
    const float* __restrict__ q, const float* __restrict__ k,
    const float* __restrict__ v, u16* __restrict__ dst) {
  const int z = blockIdx.z;
  const float* src = z == 0 ? q : z == 1 ? k : v;
  u16* d = dst + (long long)z * NB * SEQ * DM;
  long long i = ((long long)blockIdx.x * 256 + threadIdx.x) * 8;
  float4 f0 = *(const float4*)&src[i];
  float4 f1 = *(const float4*)&src[i + 4];
  u16x8 o;
  o[0] = f2bf(f0.x); o[1] = f2bf(f0.y); o[2] = f2bf(f0.z); o[3] = f2bf(f0.w);
  o[4] = f2bf(f1.x); o[5] = f2bf(f1.y); o[6] = f2bf(f1.z); o[7] = f2bf(f1.w);
  *(u16x8*)&d[i] = o;
}

extern "C" void kernel_launch(void* const* d_in, const int* in_sizes, int n_in,
                              void* d_out, int out_size, void* d_ws, size_t ws_size,
                              hipStream_t stream) {
  const float* query = (const float*)d_in[0];
  const float* key   = (const float*)d_in[1];
  const float* value = (const float*)d_in[2];
  const float* mask  = (const float*)d_in[3];
  const float* Wq = (const float*)d_in[4];
  const float* bq = (const float*)d_in[5];
  const float* Wk = (const float*)d_in[6];
  const float* bk = (const float*)d_in[7];
  const float* Wv = (const float*)d_in[8];
  const float* bv = (const float*)d_in[9];
  const float* Wo = (const float*)d_in[10];
  const float* bo = (const float*)d_in[11];
  const float* gamma = (const float*)d_in[12];
  const float* beta  = (const float*)d_in[13];

  const long long TOK = (long long)NB * SEQ;        // 8192
  float* out  = (float*)d_out;                      // [TOK, DM] fp32
  float* attn = out + TOK * DM;                     // [NB,NH,SEQ,SEQ] fp32

  // ws: 3 bf16 slots of TOK*DM (37.75 MB total)
  u16* s0 = (u16*)d_ws;            // Qh [B,H,S,DH]
  u16* s1 = s0 + TOK * DM;         // Kh [B,H,S,DH] -> later X fp32 (s1+s2)
  u16* s2 = s1 + TOK * DM;         // VT [B,H,DH,S]
  float* X = (float*)s1;           // [TOK, DM] fp32 == s1..s2 exactly

  // scratch in dead d_out regions:
  u16* WqT = (u16*)d_out;          // out region dead until final LN
  u16* WoT = WqT + 3 * (long long)DM * DM;
  u16* ctx = WqT + 4 * (long long)DM * DM;  // bf16 [TOK,DM], 12.6 MB, fits
  u16* qB = (u16*)attn;            // attn region dead until attn_fused writes

  // 1) weights -> bf16 transposed (WqT, WkT, WvT, WoT contiguous)
  castT_w<<<dim3(12, 12, 4), 256, 0, stream>>>(Wq, Wk, Wv, Wo, WqT);
  // 2) q,k,v -> bf16 (in attn-region scratch)
  cast3_bf16<<<dim3(3072, 1, 3), 256, 0, stream>>>(query, key, value, qB);

  // 3) merged QKV projections: M=8192, N=768, K=768, z over {Q,K,V}
  gemm_qkv<<<dim3(64, 6, 3), 256, 0, stream>>>(qB, WqT, bq, bk, bv, s0);

  // 4) fused attention: scores + softmax + attn-write + P@V in one kernel.
  attn_fused<<<dim3(768, 1, 1), 256, 0, stream>>>(s0, s1, s2, mask, attn, ctx);

  // 5) out projection + bias + residual -> X fp32 (Kh,VT dead)
  gemm_bt<128,128,4><<<dim3(64, 6, 1), 256, 0, stream>>>(
      ctx, DM, 0, WoT, DM, 0, bo, query, X, DM);

  // 6) LayerNorm -> out (overwrites WqT../ctx scratch, now dead)
  layernorm_rows<<<(int)(TOK / 4), 256, 0, stream>>>(X, gamma, beta, out);
}